// Round 17
// baseline (230.047 us; speedup 1.0000x reference)
//
#include <hip/hip_runtime.h>
#include <math.h>

#define NGRAPH 128
#define NPB 128          // nodes per fine bucket
#define CAPB 6144        // fine bucket capacity (mean 4096, +32 sigma)
#define MMN 16           // nodes per mm12 block
#define TILEA 8192       // edges per binA workgroup (r17: halved -> 391 blocks, all CUs)
#define EPTA 8           // TILEA / 1024 threads

// ---------------- fp8 e4m3fn helpers (payload-only; accumulation stays f32) ----

__device__ inline unsigned char f2fp8(float f) {
    float a = fabsf(f);
    unsigned s = (__float_as_uint(f) >> 31) << 7;
    if (!(a > 0.f)) return (unsigned char)s;
    if (a >= 448.f) return (unsigned char)(s | 0x7e);
    int e = (int)(__float_as_uint(a) >> 23) - 127;
    if (e < -6) e = -6;
    // 2^(3-e) built from exponent bits (e in [-6,8] -> biased 122..136): exact, no exp2f
    float sc = __uint_as_float((unsigned)(130 - e) << 23);
    int q = (int)rintf(a * sc);   // RNE
    if (q >= 16) { e += 1; q = 8; }
    if (q <= 0) return (unsigned char)s;
    unsigned expb, man;
    if (q < 8) { expb = 0; man = (unsigned)q; }
    else { expb = (unsigned)(e + 7); man = (unsigned)(q - 8); }
    return (unsigned char)(s | (expb << 3) | man);
}

typedef float v2f __attribute__((ext_vector_type(2)));

// decode 4 fp8 (one u32) -> 4 f32, register-only (fallback path only)
__device__ inline void fp8x4_dec(unsigned u, float* o) {
#pragma unroll
    for (int k = 0; k < 4; ++k) {
        unsigned b = (u >> (8 * k)) & 0xffu;
        unsigned bits = ((b & 0x80u) << 24) | ((b & 0x7fu) << 20);
        o[k] = __uint_as_float(bits) * 0x1p+120f;
    }
}

// decode one fp8 row-quad (16 values) and accumulate with weight w in {0,1}.
__device__ inline void acc16(uint4 u, float w, v2f* a) {
#if __has_builtin(__builtin_amdgcn_cvt_pk_f32_fp8)
    v2f ws; ws.x = w; ws.y = w;
    a[0] += __builtin_amdgcn_cvt_pk_f32_fp8(u.x, false) * ws;
    a[1] += __builtin_amdgcn_cvt_pk_f32_fp8(u.x, true)  * ws;
    a[2] += __builtin_amdgcn_cvt_pk_f32_fp8(u.y, false) * ws;
    a[3] += __builtin_amdgcn_cvt_pk_f32_fp8(u.y, true)  * ws;
    a[4] += __builtin_amdgcn_cvt_pk_f32_fp8(u.z, false) * ws;
    a[5] += __builtin_amdgcn_cvt_pk_f32_fp8(u.z, true)  * ws;
    a[6] += __builtin_amdgcn_cvt_pk_f32_fp8(u.w, false) * ws;
    a[7] += __builtin_amdgcn_cvt_pk_f32_fp8(u.w, true)  * ws;
#else
    float* af = (float*)a;
    unsigned uu[4] = {u.x, u.y, u.z, u.w};
#pragma unroll
    for (int q = 0; q < 4; ++q) {
        float d[4]; fp8x4_dec(uu[q], d);
#pragma unroll
        for (int k = 0; k < 4; ++k) af[q * 4 + k] += d[k] * w;
    }
#endif
}

// ---------------- init: cursors + pooled zero ----------------

__global__ void init_k(int* __restrict__ cursorF, float* __restrict__ pooled, int NBF) {
    int i = blockIdx.x * blockDim.x + threadIdx.x;
    if (i < NBF) cursorF[i] = i * CAPB;
    if (i < NGRAPH * 64) pooled[i] = 0.0f;
}

// ---------------- single-pass fine binning, LDS-staged sorted output ----------
// r11 (verified): counting-sort the tile in LDS, copy out one WAVE per
// bucket-run as contiguous bursts (kills the 5-7x write amplification of
// scattered 4B stores, r9/r10). r17: TILEA 16384->8192 with 1024 threads —
// 391 blocks instead of 196 (r9 diagnosis: 0.77 blocks/CU left 60 CUs idle;
// per-block serial LDS-atomic chain also halves 32K->16K). Extra run-boundary
// write cost ~+10 MB, dwarfed by the parallelism gain.
// Record: src (bits 0-16) | node-within-bucket (bits 17-23).

__global__ __launch_bounds__(1024) void binA_k(const int* __restrict__ src,
        const int* __restrict__ dst, int* cursorF, unsigned* __restrict__ binned,
        int E, int NBF) {
    __shared__ int lh[1024];          // histogram -> running local cursor
    __shared__ int startv[1024];      // local prefix (NBF+1 used)
    __shared__ int gdelta[1024];      // gbase - localstart per bucket
    __shared__ unsigned lout[TILEA];  // 32 KB staged sorted tile
    int tid = threadIdx.x;
    lh[tid] = 0;
    __syncthreads();
    int base = blockIdx.x * TILEA;
    int d[EPTA];
    int s[EPTA];
#pragma unroll
    for (int u = 0; u < EPTA; ++u) {
        int e = base + tid + u * 1024;
        d[u] = (e < E) ? dst[e] : -1;
        s[u] = (e < E) ? src[e] : 0;
    }
#pragma unroll
    for (int u = 0; u < EPTA; ++u)
        if (d[u] >= 0) atomicAdd(&lh[d[u] >> 7], 1);
    __syncthreads();
    // inclusive scan over NBF counts -> startv[0..NBF]
    if (tid <= NBF) startv[tid] = (tid == 0) ? 0 : lh[tid - 1];
    __syncthreads();
    for (int off = 1; off <= NBF; off <<= 1) {
        int v = 0;
        if (tid <= NBF && tid >= off) v = startv[tid - off];
        __syncthreads();
        if (tid <= NBF && tid >= off) startv[tid] += v;
        __syncthreads();
    }
    // claim global ranges; set local running cursors
    if (tid < NBF) {
        int cnt = lh[tid];
        int g = cnt ? atomicAdd(&cursorF[tid], cnt) : 0;
        gdelta[tid] = g - startv[tid];
        lh[tid] = startv[tid];
    }
    __syncthreads();
    // counting-sort scatter into LDS
#pragma unroll
    for (int u = 0; u < EPTA; ++u) {
        if (d[u] >= 0) {
            int p = atomicAdd(&lh[d[u] >> 7], 1);
            lout[p] = (unsigned)s[u] | ((unsigned)(d[u] & (NPB - 1)) << 17);
        }
    }
    __syncthreads();
    // copy out: one wave per bucket-run, lanes burst-write the run
    int wv = tid >> 6, ln = tid & 63;
    for (int bkt = wv; bkt < NBF; bkt += 16) {
        int ls = startv[bkt], le = lh[bkt];
        int gd = gdelta[bkt];
        for (int i = ls + ln; i < le; i += 64)
            binned[gd + i] = lout[i];
    }
}

// ---------------- per-fine-bucket counting sort + xs = x*dis --------
// r16: records staged in LDS on first read (lin) — deletes the 12.8 MB
// second global read of binned.

__global__ __launch_bounds__(256) void reorder_k(unsigned* __restrict__ binned,
        const int* __restrict__ cursorF, int* __restrict__ nodebeg,
        int* __restrict__ nodeend, float* __restrict__ dis,
        const float* __restrict__ x, float* __restrict__ xs, int n) {
    __shared__ int hist[NPB + 1];
    __shared__ int startv[NPB + 1];
    __shared__ unsigned lin[CAPB];
    __shared__ unsigned lout[CAPB];
    int tid = threadIdx.x;
    int b = blockIdx.x;
    int beg = b * CAPB, end = cursorF[b];
    int total = end - beg;
    if (tid <= NPB) hist[tid] = 0;
    for (int i = tid; i < total; i += 256) lin[i] = binned[beg + i];
    __syncthreads();
    for (int i = tid; i < total; i += 256)
        atomicAdd(&hist[lin[i] >> 17], 1);
    __syncthreads();
    if (tid < NPB) startv[tid + 1] = hist[tid];
    if (tid == 0) startv[0] = 0;
    __syncthreads();
    for (int off = 1; off <= NPB; off <<= 1) {
        int v = 0;
        if (tid <= NPB && tid >= off) v = startv[tid - off];
        __syncthreads();
        if (tid <= NPB && tid >= off) startv[tid] += v;
        __syncthreads();
    }
    if (tid < NPB) hist[tid] = startv[tid];
    __syncthreads();
    for (int i = tid; i < total; i += 256) {
        unsigned r = lin[i];
        int p = atomicAdd(&hist[r >> 17], 1);
        lout[p] = r & 0x1FFFFu;
    }
    __syncthreads();
    for (int jj = tid; jj < total; jj += 256)
        binned[beg + jj] = lout[jj];
    int node0 = b * NPB;
    if (tid < NPB) {
        int node = node0 + tid;
        if (node < n) {
            nodebeg[node] = beg + startv[tid];
            nodeend[node] = beg + startv[tid + 1];
            int deg = startv[tid + 1] - startv[tid];
            float d = rsqrtf((float)deg + 1.0f);
            dis[node] = d;
            xs[node * 3]     = x[node * 3] * d;
            xs[node * 3 + 1] = x[node * 3 + 1] * d;
            xs[node * 3 + 2] = x[node * 3 + 2] * d;
        }
    }
}

// ---------------- fused layer-1: gather(xs) + tb = fp8(dis * relu(y@W1+b1)@W2) ----
// r11 phase-2 (register W2 column) + r15 4-deep phase-1 batch. Single tb
// (r16's channel split REVERTED: doubled csr stream defeated the L2-residency
// gain, total +7.5 µs).

__global__ __launch_bounds__(256) void mm12_k(const float* __restrict__ xs,
        const int* __restrict__ nodebeg, const int* __restrict__ nodeend,
        const int* __restrict__ csr, const float* __restrict__ dis,
        const float* __restrict__ W1, const float* __restrict__ b1,
        const float* __restrict__ W2, unsigned char* __restrict__ tb, int n) {
    __shared__ __attribute__((aligned(16))) float hrow[4][64];
    __shared__ float4 ytile[MMN];
    int tid = threadIdx.x;
    int j = tid & 63;

    // register column of the weights (issued first; latency hides under phase 1)
    float w1r0 = W1[j], w1r1 = W1[64 + j], w1r2 = W1[128 + j], bbr = b1[j];
    float wreg[64];
#pragma unroll
    for (int k = 0; k < 64; ++k) wreg[k] = W2[k * 64 + j];

    // ---- phase 1: gather y for this block's 16 nodes (4-deep batch) ----
    int ns = tid >> 4;          // node slot 0..15
    int el = tid & 15;          // edge lane 0..15
    int gnode = blockIdx.x * MMN + ns;
    float a0 = 0.f, a1 = 0.f, a2 = 0.f;
    float dn = 0.f;
    int b = 0, e = 0;
    if (gnode < n) {
        dn = dis[gnode];
        b = nodebeg[gnode];
        e = nodeend[gnode];
    }
    for (int i = b + el; i < e; i += 64) {
        int i1 = i + 16, i2 = i + 32, i3 = i + 48;
        int s0 = csr[i];
        int s1 = (i1 < e) ? csr[i1] : s0;
        int s2 = (i2 < e) ? csr[i2] : s0;
        int s3 = (i3 < e) ? csr[i3] : s0;
        float m1 = (i1 < e) ? 1.f : 0.f;
        float m2 = (i2 < e) ? 1.f : 0.f;
        float m3 = (i3 < e) ? 1.f : 0.f;
        float p0 = xs[s0 * 3], p1 = xs[s0 * 3 + 1], p2 = xs[s0 * 3 + 2];
        float q0 = xs[s1 * 3], q1 = xs[s1 * 3 + 1], q2 = xs[s1 * 3 + 2];
        float r0 = xs[s2 * 3], r1 = xs[s2 * 3 + 1], r2 = xs[s2 * 3 + 2];
        float t0 = xs[s3 * 3], t1 = xs[s3 * 3 + 1], t2 = xs[s3 * 3 + 2];
        a0 += p0 + q0 * m1 + r0 * m2 + t0 * m3;
        a1 += p1 + q1 * m1 + r1 * m2 + t1 * m3;
        a2 += p2 + q2 * m1 + r2 * m2 + t2 * m3;
    }
    // reduce over the 16 edge lanes (lane-group-local xor shuffles)
#pragma unroll
    for (int off = 1; off <= 8; off <<= 1) {
        a0 += __shfl_xor(a0, off);
        a1 += __shfl_xor(a1, off);
        a2 += __shfl_xor(a2, off);
    }
    if (el == 0 && gnode < n) {
        // self term: dn*x[node] == xs[node]; y = dn*(sum + xs[node])
        ytile[ns] = make_float4(dn * (a0 + xs[gnode * 3]),
                                dn * (a1 + xs[gnode * 3 + 1]),
                                dn * (a2 + xs[gnode * 3 + 2]), dn);
    }
    __syncthreads();   // the ONLY block barrier: ytile ready

    // ---- phase 2: MLP (hrow is wave-private; w2 column in registers) ----
    int nl = tid >> 6;
    for (int it = 0; it < MMN / 4; ++it) {
        int slot = it * 4 + nl;
        int node = blockIdx.x * MMN + slot;
        float4 yv = ytile[slot];
        float h = fmaxf(yv.x * w1r0 + yv.y * w1r1 + yv.z * w1r2 + bbr, 0.0f);
        hrow[nl][j] = h;
        __builtin_amdgcn_wave_barrier();   // compiler fence only (no HW cost)
        float acc = 0.0f;
#pragma unroll
        for (int k = 0; k < 64; k += 4) {
            float4 h4 = *(const float4*)&hrow[nl][k];
            acc += h4.x * wreg[k + 0];
            acc += h4.y * wreg[k + 1];
            acc += h4.z * wreg[k + 2];
            acc += h4.w * wreg[k + 3];
        }
        if (node < n) tb[node * 64 + j] = f2fp8(acc * yv.w);  // store u = t*dis(node)
        __builtin_amdgcn_wave_barrier();   // keep next-iter hrow write below these reads
    }
}

// ---------------- layer 2 aggregate + fused relu-pool (r15 form, verified) ----
// 2 nodes/wave; esub in [0,8) x c4 in [0,4); 8-deep staging (64 slots = one
// latency exposure); 3-stage reduce-scatter (xor 4/8/16); relu + LDS graph-bin
// pooling, one flush of <=256 global atomics per block (NOT r4's per-lane
// atomic storm). tb holds u = t*dis so edge weight is 1 (r9 pre-scaling).

__global__ __launch_bounds__(256) void gather2_k(const unsigned char* __restrict__ tb,
        const float* __restrict__ b2, const int* __restrict__ nodebeg,
        const int* __restrict__ nodeend, const int* __restrict__ csr,
        const float* __restrict__ dis, const int* __restrict__ batch,
        float* __restrict__ pooled, int n) {
    __shared__ float pacc[4][64];
    __shared__ int gbase;
    int tid = threadIdx.x;
    ((float*)pacc)[tid] = 0.f;
    int node0 = blockIdx.x * 8;              // 8 nodes per 256-thread block
    if (tid == 0) gbase = batch[node0 < n ? node0 : (n - 1)];
    __syncthreads();

    int g = blockIdx.x * blockDim.x + tid;
    int node = g >> 5;                       // 32 lanes per node
    int l32 = tid & 31;
    int c4 = l32 & 3, esub = l32 >> 2;       // esub in [0,8)
    if (node < n) {
        const uint4* t16 = (const uint4*)tb; // row = 4 uint4 (64 fp8)
        float dn = dis[node];
        int b = nodebeg[node], e = nodeend[node];
        v2f av[8];
#pragma unroll
        for (int k = 0; k < 8; ++k) { av[k].x = 0.f; av[k].y = 0.f; }
        // slots i+esub+8d, d=0..7 cover i..i+63 exactly once; slot idx==e carries
        // the self-loop (s=node, weight 1); slots > e weight 0.
        for (int i = b; i < e + 1; i += 64) {
            int i0 = i + esub;
            int s0 = (i0      < e) ? csr[i0]      : node;
            int s1 = (i0 + 8  < e) ? csr[i0 + 8]  : node;
            int s2 = (i0 + 16 < e) ? csr[i0 + 16] : node;
            int s3 = (i0 + 24 < e) ? csr[i0 + 24] : node;
            int s4 = (i0 + 32 < e) ? csr[i0 + 32] : node;
            int s5 = (i0 + 40 < e) ? csr[i0 + 40] : node;
            int s6 = (i0 + 48 < e) ? csr[i0 + 48] : node;
            int s7 = (i0 + 56 < e) ? csr[i0 + 56] : node;
            uint4 u0 = t16[s0 * 4 + c4];
            uint4 u1 = t16[s1 * 4 + c4];
            uint4 u2 = t16[s2 * 4 + c4];
            uint4 u3 = t16[s3 * 4 + c4];
            uint4 u4 = t16[s4 * 4 + c4];
            uint4 u5 = t16[s5 * 4 + c4];
            uint4 u6 = t16[s6 * 4 + c4];
            uint4 u7 = t16[s7 * 4 + c4];
            acc16(u0, (i0      <= e) ? 1.f : 0.f, av);
            acc16(u1, (i0 + 8  <= e) ? 1.f : 0.f, av);
            acc16(u2, (i0 + 16 <= e) ? 1.f : 0.f, av);
            acc16(u3, (i0 + 24 <= e) ? 1.f : 0.f, av);
            acc16(u4, (i0 + 32 <= e) ? 1.f : 0.f, av);
            acc16(u5, (i0 + 40 <= e) ? 1.f : 0.f, av);
            acc16(u6, (i0 + 48 <= e) ? 1.f : 0.f, av);
            acc16(u7, (i0 + 56 <= e) ? 1.f : 0.f, av);
        }
        float* a = (float*)av;               // a[k] = channel c4*16 + k
        // reduce-scatter over the 8 esub lanes (intra-half xor shuffles).
        {
            bool hi = (esub & 1) != 0;       // stage off=4 (esub bit0)
#pragma unroll
            for (int t = 0; t < 8; ++t) {
                float send = hi ? a[t] : a[8 + t];
                float r = __shfl_xor(send, 4);
                a[t] = (hi ? a[8 + t] : a[t]) + r;
            }
        }
        {
            bool hi = (esub & 2) != 0;       // stage off=8 (esub bit1)
#pragma unroll
            for (int t = 0; t < 4; ++t) {
                float send = hi ? a[t] : a[4 + t];
                float r = __shfl_xor(send, 8);
                a[t] = (hi ? a[4 + t] : a[t]) + r;
            }
        }
        {
            bool hi = (esub & 4) != 0;       // stage off=16 (esub bit2)
#pragma unroll
            for (int t = 0; t < 2; ++t) {
                float send = hi ? a[t] : a[2 + t];
                float r = __shfl_xor(send, 16);
                a[t] = (hi ? a[2 + t] : a[t]) + r;
            }
        }
        // lane holds channels cb, cb+1: cb = bit0*8 + bit1*4 + bit2*2 (even 0..14)
        int cb = ((esub & 1) << 3) | ((esub & 2) << 1) | ((esub & 4) >> 1);
        int ch = c4 * 16 + cb;
        v2f bv = *(const v2f*)&b2[ch];
        float v0 = fmaxf(dn * a[0] + bv.x, 0.f);
        float v1 = fmaxf(dn * a[1] + bv.y, 0.f);
        int gid = batch[node];
        int bin = gid - gbase;
        if (bin < 4) {
            atomicAdd(&pacc[bin][ch], v0);
            atomicAdd(&pacc[bin][ch + 1], v1);
        } else {   // pathological tiny-graph fallback (practically never)
            atomicAdd(&pooled[gid * 64 + ch], v0);
            atomicAdd(&pooled[gid * 64 + ch + 1], v1);
        }
    }
    __syncthreads();
    // flush: 256 threads cover 4 bins x 64 channels; skip empty (relu >= 0)
    int fbin = tid >> 6, fch = tid & 63;
    float fv = pacc[fbin][fch];
    if (fv != 0.f) atomicAdd(&pooled[(gbase + fbin) * 64 + fch], fv);
}

// ---------------- head ----------------

__device__ inline int lower_bound_i(const int* a, int n, int key) {
    int lo = 0, hi = n;
    while (lo < hi) {
        int mid = (lo + hi) >> 1;
        if (a[mid] < key) lo = mid + 1; else hi = mid;
    }
    return lo;
}

__global__ void head_k(const float* __restrict__ pooled, const int* __restrict__ batch,
                       const float* __restrict__ Wl, const float* __restrict__ bl,
                       float* __restrict__ out, int n) {
    int g = blockIdx.x, t = threadIdx.x;
    __shared__ float p[64];
    __shared__ float logit[8];
    int start = lower_bound_i(batch, n, g);
    int end   = lower_bound_i(batch, n, g + 1);
    float cnt = fmaxf((float)(end - start), 1.0f);
    p[t] = pooled[g * 64 + t] / cnt;
    __syncthreads();
    if (t < 6) {
        float a = bl[t];
        for (int k = 0; k < 64; ++k) a += p[k] * Wl[k * 6 + t];
        logit[t] = a;
    }
    __syncthreads();
    if (t == 0) {
        float m = logit[0];
        for (int j = 1; j < 6; ++j) m = fmaxf(m, logit[j]);
        float s = 0.0f;
        for (int j = 0; j < 6; ++j) s += expf(logit[j] - m);
        float lse = m + logf(s);
        for (int j = 0; j < 6; ++j) out[g * 6 + j] = logit[j] - lse;
    }
}

// ---------------- launch ----------------

extern "C" void kernel_launch(void* const* d_in, const int* in_sizes, int n_in,
                              void* d_out, int out_size, void* d_ws, size_t ws_size,
                              hipStream_t stream) {
    const float* x     = (const float*)d_in[0];
    const int*   ei    = (const int*)d_in[1];
    const int*   batch = (const int*)d_in[2];
    const float* W1    = (const float*)d_in[3];
    const float* b1    = (const float*)d_in[4];
    const float* W2    = (const float*)d_in[5];
    const float* b2    = (const float*)d_in[6];
    const float* Wl    = (const float*)d_in[7];
    const float* bl    = (const float*)d_in[8];

    int n = in_sizes[0] / 3;
    int E = in_sizes[1] / 2;
    const int* src = ei;
    const int* dst = ei + E;

    int NBF = (n + NPB - 1) / NPB;          // fine buckets (782)
    int GA = (E + TILEA - 1) / TILEA;       // binA blocks (391)

    char* ws = (char*)d_ws;
    size_t o = 0;
    auto alloc = [&](size_t bytes) -> void* {
        void* p = ws + o;
        o += (bytes + 255) & ~(size_t)255;
        return p;
    };
    int*      cursorF = (int*)alloc((size_t)NBF * 4);
    float*    dis     = (float*)alloc((size_t)n * 4);
    int*      nodebeg = (int*)alloc((size_t)n * 4);
    int*      nodeend = (int*)alloc((size_t)n * 4);
    float*    xs      = (float*)alloc((size_t)n * 3 * 4);
    float*    pooled  = (float*)alloc((size_t)NGRAPH * 64 * 4);
    unsigned* binned  = (unsigned*)alloc((size_t)NBF * CAPB * 4);  // becomes csr in-place
    unsigned char* tb = (unsigned char*)alloc((size_t)n * 64);     // fp8 u = t*dis
    float*    out = (float*)d_out;

    int initN = NGRAPH * 64;  // 8192 > NBF
    init_k<<<(initN + 255) / 256, 256, 0, stream>>>(cursorF, pooled, NBF);
    binA_k<<<GA, 1024, 0, stream>>>(src, dst, cursorF, binned, E, NBF);
    reorder_k<<<NBF, 256, 0, stream>>>(binned, cursorF, nodebeg, nodeend, dis, x, xs, n);

    mm12_k<<<(n + MMN - 1) / MMN, 256, 0, stream>>>(xs, nodebeg, nodeend,
            (const int*)binned, dis, W1, b1, W2, tb, n);
    gather2_k<<<(n * 32 + 255) / 256, 256, 0, stream>>>(tb, b2, nodebeg, nodeend,
            (const int*)binned, dis, batch, pooled, n);

    head_k<<<NGRAPH, 64, 0, stream>>>(pooled, batch, Wl, bl, out, n);
}

// Round 18
// 224.103 us; speedup vs baseline: 1.0265x; 1.0265x over previous
//
#include <hip/hip_runtime.h>
#include <math.h>

#define NGRAPH 128
#define NPB 128          // nodes per fine bucket
#define CAPB 6144        // fine bucket capacity (mean 4096, +32 sigma)
#define MMN 16           // nodes per mm12 block
#define TILEA 16384      // edges per binA workgroup (r18: restored — 8192 measured +11 µs)
#define EPTA 16          // TILEA / 1024 threads

// ---------------- fp8 e4m3fn helpers (payload-only; accumulation stays f32) ----

__device__ inline unsigned char f2fp8(float f) {
    float a = fabsf(f);
    unsigned s = (__float_as_uint(f) >> 31) << 7;
    if (!(a > 0.f)) return (unsigned char)s;
    if (a >= 448.f) return (unsigned char)(s | 0x7e);
    int e = (int)(__float_as_uint(a) >> 23) - 127;
    if (e < -6) e = -6;
    // 2^(3-e) built from exponent bits (e in [-6,8] -> biased 122..136): exact, no exp2f
    float sc = __uint_as_float((unsigned)(130 - e) << 23);
    int q = (int)rintf(a * sc);   // RNE
    if (q >= 16) { e += 1; q = 8; }
    if (q <= 0) return (unsigned char)s;
    unsigned expb, man;
    if (q < 8) { expb = 0; man = (unsigned)q; }
    else { expb = (unsigned)(e + 7); man = (unsigned)(q - 8); }
    return (unsigned char)(s | (expb << 3) | man);
}

typedef float v2f __attribute__((ext_vector_type(2)));

// decode 4 fp8 (one u32) -> 4 f32, register-only (fallback path only)
__device__ inline void fp8x4_dec(unsigned u, float* o) {
#pragma unroll
    for (int k = 0; k < 4; ++k) {
        unsigned b = (u >> (8 * k)) & 0xffu;
        unsigned bits = ((b & 0x80u) << 24) | ((b & 0x7fu) << 20);
        o[k] = __uint_as_float(bits) * 0x1p+120f;
    }
}

// decode one fp8 row-quad (16 values) and accumulate with weight w in {0,1}.
__device__ inline void acc16(uint4 u, float w, v2f* a) {
#if __has_builtin(__builtin_amdgcn_cvt_pk_f32_fp8)
    v2f ws; ws.x = w; ws.y = w;
    a[0] += __builtin_amdgcn_cvt_pk_f32_fp8(u.x, false) * ws;
    a[1] += __builtin_amdgcn_cvt_pk_f32_fp8(u.x, true)  * ws;
    a[2] += __builtin_amdgcn_cvt_pk_f32_fp8(u.y, false) * ws;
    a[3] += __builtin_amdgcn_cvt_pk_f32_fp8(u.y, true)  * ws;
    a[4] += __builtin_amdgcn_cvt_pk_f32_fp8(u.z, false) * ws;
    a[5] += __builtin_amdgcn_cvt_pk_f32_fp8(u.z, true)  * ws;
    a[6] += __builtin_amdgcn_cvt_pk_f32_fp8(u.w, false) * ws;
    a[7] += __builtin_amdgcn_cvt_pk_f32_fp8(u.w, true)  * ws;
#else
    float* af = (float*)a;
    unsigned uu[4] = {u.x, u.y, u.z, u.w};
#pragma unroll
    for (int q = 0; q < 4; ++q) {
        float d[4]; fp8x4_dec(uu[q], d);
#pragma unroll
        for (int k = 0; k < 4; ++k) af[q * 4 + k] += d[k] * w;
    }
#endif
}

// ---------------- init: cursors + pooled zero ----------------

__global__ void init_k(int* __restrict__ cursorF, float* __restrict__ pooled, int NBF) {
    int i = blockIdx.x * blockDim.x + threadIdx.x;
    if (i < NBF) cursorF[i] = i * CAPB;
    if (i < NGRAPH * 64) pooled[i] = 0.0f;
}

// ---------------- single-pass fine binning, LDS-staged sorted output ----------
// r11 (verified): counting-sort the 16K-edge tile in LDS, copy out one WAVE
// per bucket-run as contiguous bursts (kills the 5-7x write amplification of
// scattered 4B stores, r9/r10). TILEA=16384 is the measured optimum: 8192
// (r17) cost +11 µs (shorter runs -> more partial boundary lines + 2x claim/
// copy overhead outweighed the extra block parallelism).
// Record: src (bits 0-16) | node-within-bucket (bits 17-23).

__global__ __launch_bounds__(1024) void binA_k(const int* __restrict__ src,
        const int* __restrict__ dst, int* cursorF, unsigned* __restrict__ binned,
        int E, int NBF) {
    __shared__ int lh[1024];          // histogram -> running local cursor
    __shared__ int startv[1024];      // local prefix (NBF+1 used)
    __shared__ int gdelta[1024];      // gbase - localstart per bucket
    __shared__ unsigned lout[TILEA];  // 64 KB staged sorted tile
    int tid = threadIdx.x;
    lh[tid] = 0;
    __syncthreads();
    int base = blockIdx.x * TILEA;
    int d[EPTA];
    int s[EPTA];
#pragma unroll
    for (int u = 0; u < EPTA; ++u) {
        int e = base + tid + u * 1024;
        d[u] = (e < E) ? dst[e] : -1;
        s[u] = (e < E) ? src[e] : 0;
    }
#pragma unroll
    for (int u = 0; u < EPTA; ++u)
        if (d[u] >= 0) atomicAdd(&lh[d[u] >> 7], 1);
    __syncthreads();
    // inclusive scan over NBF counts -> startv[0..NBF]
    if (tid <= NBF) startv[tid] = (tid == 0) ? 0 : lh[tid - 1];
    __syncthreads();
    for (int off = 1; off <= NBF; off <<= 1) {
        int v = 0;
        if (tid <= NBF && tid >= off) v = startv[tid - off];
        __syncthreads();
        if (tid <= NBF && tid >= off) startv[tid] += v;
        __syncthreads();
    }
    // claim global ranges; set local running cursors
    if (tid < NBF) {
        int cnt = lh[tid];
        int g = cnt ? atomicAdd(&cursorF[tid], cnt) : 0;
        gdelta[tid] = g - startv[tid];
        lh[tid] = startv[tid];
    }
    __syncthreads();
    // counting-sort scatter into LDS
#pragma unroll
    for (int u = 0; u < EPTA; ++u) {
        if (d[u] >= 0) {
            int p = atomicAdd(&lh[d[u] >> 7], 1);
            lout[p] = (unsigned)s[u] | ((unsigned)(d[u] & (NPB - 1)) << 17);
        }
    }
    __syncthreads();
    // copy out: one wave per bucket-run, lanes burst-write the run
    int wv = tid >> 6, ln = tid & 63;
    for (int bkt = wv; bkt < NBF; bkt += 16) {
        int ls = startv[bkt], le = lh[bkt];
        int gd = gdelta[bkt];
        for (int i = ls + ln; i < le; i += 64)
            binned[gd + i] = lout[i];
    }
}

// ---------------- per-fine-bucket counting sort + xs = x*dis --------
// r16: records staged in LDS on first read (lin) — deletes the 12.8 MB
// second global read of binned (isolated effect ~neutral, kept).

__global__ __launch_bounds__(256) void reorder_k(unsigned* __restrict__ binned,
        const int* __restrict__ cursorF, int* __restrict__ nodebeg,
        int* __restrict__ nodeend, float* __restrict__ dis,
        const float* __restrict__ x, float* __restrict__ xs, int n) {
    __shared__ int hist[NPB + 1];
    __shared__ int startv[NPB + 1];
    __shared__ unsigned lin[CAPB];
    __shared__ unsigned lout[CAPB];
    int tid = threadIdx.x;
    int b = blockIdx.x;
    int beg = b * CAPB, end = cursorF[b];
    int total = end - beg;
    if (tid <= NPB) hist[tid] = 0;
    for (int i = tid; i < total; i += 256) lin[i] = binned[beg + i];
    __syncthreads();
    for (int i = tid; i < total; i += 256)
        atomicAdd(&hist[lin[i] >> 17], 1);
    __syncthreads();
    if (tid < NPB) startv[tid + 1] = hist[tid];
    if (tid == 0) startv[0] = 0;
    __syncthreads();
    for (int off = 1; off <= NPB; off <<= 1) {
        int v = 0;
        if (tid <= NPB && tid >= off) v = startv[tid - off];
        __syncthreads();
        if (tid <= NPB && tid >= off) startv[tid] += v;
        __syncthreads();
    }
    if (tid < NPB) hist[tid] = startv[tid];
    __syncthreads();
    for (int i = tid; i < total; i += 256) {
        unsigned r = lin[i];
        int p = atomicAdd(&hist[r >> 17], 1);
        lout[p] = r & 0x1FFFFu;
    }
    __syncthreads();
    for (int jj = tid; jj < total; jj += 256)
        binned[beg + jj] = lout[jj];
    int node0 = b * NPB;
    if (tid < NPB) {
        int node = node0 + tid;
        if (node < n) {
            nodebeg[node] = beg + startv[tid];
            nodeend[node] = beg + startv[tid + 1];
            int deg = startv[tid + 1] - startv[tid];
            float d = rsqrtf((float)deg + 1.0f);
            dis[node] = d;
            xs[node * 3]     = x[node * 3] * d;
            xs[node * 3 + 1] = x[node * 3 + 1] * d;
            xs[node * 3 + 2] = x[node * 3 + 2] * d;
        }
    }
}

// ---------------- fused layer-1: gather(xs) + tb = fp8(dis * relu(y@W1+b1)@W2) ----
// r11 phase-2 (register W2 column) + r15 4-deep phase-1 batch. Single tb
// (r16's channel split REVERTED: doubled csr stream defeated the L2-residency
// gain, +7.5 µs).

__global__ __launch_bounds__(256) void mm12_k(const float* __restrict__ xs,
        const int* __restrict__ nodebeg, const int* __restrict__ nodeend,
        const int* __restrict__ csr, const float* __restrict__ dis,
        const float* __restrict__ W1, const float* __restrict__ b1,
        const float* __restrict__ W2, unsigned char* __restrict__ tb, int n) {
    __shared__ __attribute__((aligned(16))) float hrow[4][64];
    __shared__ float4 ytile[MMN];
    int tid = threadIdx.x;
    int j = tid & 63;

    // register column of the weights (issued first; latency hides under phase 1)
    float w1r0 = W1[j], w1r1 = W1[64 + j], w1r2 = W1[128 + j], bbr = b1[j];
    float wreg[64];
#pragma unroll
    for (int k = 0; k < 64; ++k) wreg[k] = W2[k * 64 + j];

    // ---- phase 1: gather y for this block's 16 nodes (4-deep batch) ----
    int ns = tid >> 4;          // node slot 0..15
    int el = tid & 15;          // edge lane 0..15
    int gnode = blockIdx.x * MMN + ns;
    float a0 = 0.f, a1 = 0.f, a2 = 0.f;
    float dn = 0.f;
    int b = 0, e = 0;
    if (gnode < n) {
        dn = dis[gnode];
        b = nodebeg[gnode];
        e = nodeend[gnode];
    }
    for (int i = b + el; i < e; i += 64) {
        int i1 = i + 16, i2 = i + 32, i3 = i + 48;
        int s0 = csr[i];
        int s1 = (i1 < e) ? csr[i1] : s0;
        int s2 = (i2 < e) ? csr[i2] : s0;
        int s3 = (i3 < e) ? csr[i3] : s0;
        float m1 = (i1 < e) ? 1.f : 0.f;
        float m2 = (i2 < e) ? 1.f : 0.f;
        float m3 = (i3 < e) ? 1.f : 0.f;
        float p0 = xs[s0 * 3], p1 = xs[s0 * 3 + 1], p2 = xs[s0 * 3 + 2];
        float q0 = xs[s1 * 3], q1 = xs[s1 * 3 + 1], q2 = xs[s1 * 3 + 2];
        float r0 = xs[s2 * 3], r1 = xs[s2 * 3 + 1], r2 = xs[s2 * 3 + 2];
        float t0 = xs[s3 * 3], t1 = xs[s3 * 3 + 1], t2 = xs[s3 * 3 + 2];
        a0 += p0 + q0 * m1 + r0 * m2 + t0 * m3;
        a1 += p1 + q1 * m1 + r1 * m2 + t1 * m3;
        a2 += p2 + q2 * m1 + r2 * m2 + t2 * m3;
    }
    // reduce over the 16 edge lanes (lane-group-local xor shuffles)
#pragma unroll
    for (int off = 1; off <= 8; off <<= 1) {
        a0 += __shfl_xor(a0, off);
        a1 += __shfl_xor(a1, off);
        a2 += __shfl_xor(a2, off);
    }
    if (el == 0 && gnode < n) {
        // self term: dn*x[node] == xs[node]; y = dn*(sum + xs[node])
        ytile[ns] = make_float4(dn * (a0 + xs[gnode * 3]),
                                dn * (a1 + xs[gnode * 3 + 1]),
                                dn * (a2 + xs[gnode * 3 + 2]), dn);
    }
    __syncthreads();   // the ONLY block barrier: ytile ready

    // ---- phase 2: MLP (hrow is wave-private; w2 column in registers) ----
    int nl = tid >> 6;
    for (int it = 0; it < MMN / 4; ++it) {
        int slot = it * 4 + nl;
        int node = blockIdx.x * MMN + slot;
        float4 yv = ytile[slot];
        float h = fmaxf(yv.x * w1r0 + yv.y * w1r1 + yv.z * w1r2 + bbr, 0.0f);
        hrow[nl][j] = h;
        __builtin_amdgcn_wave_barrier();   // compiler fence only (no HW cost)
        float acc = 0.0f;
#pragma unroll
        for (int k = 0; k < 64; k += 4) {
            float4 h4 = *(const float4*)&hrow[nl][k];
            acc += h4.x * wreg[k + 0];
            acc += h4.y * wreg[k + 1];
            acc += h4.z * wreg[k + 2];
            acc += h4.w * wreg[k + 3];
        }
        if (node < n) tb[node * 64 + j] = f2fp8(acc * yv.w);  // store u = t*dis(node)
        __builtin_amdgcn_wave_barrier();   // keep next-iter hrow write below these reads
    }
}

// ---------------- layer 2 aggregate + fused relu-pool (r15 form, verified) ----
// 2 nodes/wave; esub in [0,8) x c4 in [0,4); 8-deep staging (64 slots = one
// latency exposure); 3-stage reduce-scatter (xor 4/8/16); relu + LDS graph-bin
// pooling, one flush of <=256 global atomics per block (NOT r4's per-lane
// atomic storm). tb holds u = t*dis so edge weight is 1 (r9 pre-scaling).

__global__ __launch_bounds__(256) void gather2_k(const unsigned char* __restrict__ tb,
        const float* __restrict__ b2, const int* __restrict__ nodebeg,
        const int* __restrict__ nodeend, const int* __restrict__ csr,
        const float* __restrict__ dis, const int* __restrict__ batch,
        float* __restrict__ pooled, int n) {
    __shared__ float pacc[4][64];
    __shared__ int gbase;
    int tid = threadIdx.x;
    ((float*)pacc)[tid] = 0.f;
    int node0 = blockIdx.x * 8;              // 8 nodes per 256-thread block
    if (tid == 0) gbase = batch[node0 < n ? node0 : (n - 1)];
    __syncthreads();

    int g = blockIdx.x * blockDim.x + tid;
    int node = g >> 5;                       // 32 lanes per node
    int l32 = tid & 31;
    int c4 = l32 & 3, esub = l32 >> 2;       // esub in [0,8)
    if (node < n) {
        const uint4* t16 = (const uint4*)tb; // row = 4 uint4 (64 fp8)
        float dn = dis[node];
        int b = nodebeg[node], e = nodeend[node];
        v2f av[8];
#pragma unroll
        for (int k = 0; k < 8; ++k) { av[k].x = 0.f; av[k].y = 0.f; }
        // slots i+esub+8d, d=0..7 cover i..i+63 exactly once; slot idx==e carries
        // the self-loop (s=node, weight 1); slots > e weight 0.
        for (int i = b; i < e + 1; i += 64) {
            int i0 = i + esub;
            int s0 = (i0      < e) ? csr[i0]      : node;
            int s1 = (i0 + 8  < e) ? csr[i0 + 8]  : node;
            int s2 = (i0 + 16 < e) ? csr[i0 + 16] : node;
            int s3 = (i0 + 24 < e) ? csr[i0 + 24] : node;
            int s4 = (i0 + 32 < e) ? csr[i0 + 32] : node;
            int s5 = (i0 + 40 < e) ? csr[i0 + 40] : node;
            int s6 = (i0 + 48 < e) ? csr[i0 + 48] : node;
            int s7 = (i0 + 56 < e) ? csr[i0 + 56] : node;
            uint4 u0 = t16[s0 * 4 + c4];
            uint4 u1 = t16[s1 * 4 + c4];
            uint4 u2 = t16[s2 * 4 + c4];
            uint4 u3 = t16[s3 * 4 + c4];
            uint4 u4 = t16[s4 * 4 + c4];
            uint4 u5 = t16[s5 * 4 + c4];
            uint4 u6 = t16[s6 * 4 + c4];
            uint4 u7 = t16[s7 * 4 + c4];
            acc16(u0, (i0      <= e) ? 1.f : 0.f, av);
            acc16(u1, (i0 + 8  <= e) ? 1.f : 0.f, av);
            acc16(u2, (i0 + 16 <= e) ? 1.f : 0.f, av);
            acc16(u3, (i0 + 24 <= e) ? 1.f : 0.f, av);
            acc16(u4, (i0 + 32 <= e) ? 1.f : 0.f, av);
            acc16(u5, (i0 + 40 <= e) ? 1.f : 0.f, av);
            acc16(u6, (i0 + 48 <= e) ? 1.f : 0.f, av);
            acc16(u7, (i0 + 56 <= e) ? 1.f : 0.f, av);
        }
        float* a = (float*)av;               // a[k] = channel c4*16 + k
        // reduce-scatter over the 8 esub lanes (intra-half xor shuffles).
        {
            bool hi = (esub & 1) != 0;       // stage off=4 (esub bit0)
#pragma unroll
            for (int t = 0; t < 8; ++t) {
                float send = hi ? a[t] : a[8 + t];
                float r = __shfl_xor(send, 4);
                a[t] = (hi ? a[8 + t] : a[t]) + r;
            }
        }
        {
            bool hi = (esub & 2) != 0;       // stage off=8 (esub bit1)
#pragma unroll
            for (int t = 0; t < 4; ++t) {
                float send = hi ? a[t] : a[4 + t];
                float r = __shfl_xor(send, 8);
                a[t] = (hi ? a[4 + t] : a[t]) + r;
            }
        }
        {
            bool hi = (esub & 4) != 0;       // stage off=16 (esub bit2)
#pragma unroll
            for (int t = 0; t < 2; ++t) {
                float send = hi ? a[t] : a[2 + t];
                float r = __shfl_xor(send, 16);
                a[t] = (hi ? a[2 + t] : a[t]) + r;
            }
        }
        // lane holds channels cb, cb+1: cb = bit0*8 + bit1*4 + bit2*2 (even 0..14)
        int cb = ((esub & 1) << 3) | ((esub & 2) << 1) | ((esub & 4) >> 1);
        int ch = c4 * 16 + cb;
        v2f bv = *(const v2f*)&b2[ch];
        float v0 = fmaxf(dn * a[0] + bv.x, 0.f);
        float v1 = fmaxf(dn * a[1] + bv.y, 0.f);
        int gid = batch[node];
        int bin = gid - gbase;
        if (bin < 4) {
            atomicAdd(&pacc[bin][ch], v0);
            atomicAdd(&pacc[bin][ch + 1], v1);
        } else {   // pathological tiny-graph fallback (practically never)
            atomicAdd(&pooled[gid * 64 + ch], v0);
            atomicAdd(&pooled[gid * 64 + ch + 1], v1);
        }
    }
    __syncthreads();
    // flush: 256 threads cover 4 bins x 64 channels; skip empty (relu >= 0)
    int fbin = tid >> 6, fch = tid & 63;
    float fv = pacc[fbin][fch];
    if (fv != 0.f) atomicAdd(&pooled[(gbase + fbin) * 64 + fch], fv);
}

// ---------------- head ----------------

__device__ inline int lower_bound_i(const int* a, int n, int key) {
    int lo = 0, hi = n;
    while (lo < hi) {
        int mid = (lo + hi) >> 1;
        if (a[mid] < key) lo = mid + 1; else hi = mid;
    }
    return lo;
}

__global__ void head_k(const float* __restrict__ pooled, const int* __restrict__ batch,
                       const float* __restrict__ Wl, const float* __restrict__ bl,
                       float* __restrict__ out, int n) {
    int g = blockIdx.x, t = threadIdx.x;
    __shared__ float p[64];
    __shared__ float logit[8];
    int start = lower_bound_i(batch, n, g);
    int end   = lower_bound_i(batch, n, g + 1);
    float cnt = fmaxf((float)(end - start), 1.0f);
    p[t] = pooled[g * 64 + t] / cnt;
    __syncthreads();
    if (t < 6) {
        float a = bl[t];
        for (int k = 0; k < 64; ++k) a += p[k] * Wl[k * 6 + t];
        logit[t] = a;
    }
    __syncthreads();
    if (t == 0) {
        float m = logit[0];
        for (int j = 1; j < 6; ++j) m = fmaxf(m, logit[j]);
        float s = 0.0f;
        for (int j = 0; j < 6; ++j) s += expf(logit[j] - m);
        float lse = m + logf(s);
        for (int j = 0; j < 6; ++j) out[g * 6 + j] = logit[j] - lse;
    }
}

// ---------------- launch ----------------

extern "C" void kernel_launch(void* const* d_in, const int* in_sizes, int n_in,
                              void* d_out, int out_size, void* d_ws, size_t ws_size,
                              hipStream_t stream) {
    const float* x     = (const float*)d_in[0];
    const int*   ei    = (const int*)d_in[1];
    const int*   batch = (const int*)d_in[2];
    const float* W1    = (const float*)d_in[3];
    const float* b1    = (const float*)d_in[4];
    const float* W2    = (const float*)d_in[5];
    const float* b2    = (const float*)d_in[6];
    const float* Wl    = (const float*)d_in[7];
    const float* bl    = (const float*)d_in[8];

    int n = in_sizes[0] / 3;
    int E = in_sizes[1] / 2;
    const int* src = ei;
    const int* dst = ei + E;

    int NBF = (n + NPB - 1) / NPB;          // fine buckets (782)
    int GA = (E + TILEA - 1) / TILEA;       // binA blocks (196)

    char* ws = (char*)d_ws;
    size_t o = 0;
    auto alloc = [&](size_t bytes) -> void* {
        void* p = ws + o;
        o += (bytes + 255) & ~(size_t)255;
        return p;
    };
    int*      cursorF = (int*)alloc((size_t)NBF * 4);
    float*    dis     = (float*)alloc((size_t)n * 4);
    int*      nodebeg = (int*)alloc((size_t)n * 4);
    int*      nodeend = (int*)alloc((size_t)n * 4);
    float*    xs      = (float*)alloc((size_t)n * 3 * 4);
    float*    pooled  = (float*)alloc((size_t)NGRAPH * 64 * 4);
    unsigned* binned  = (unsigned*)alloc((size_t)NBF * CAPB * 4);  // becomes csr in-place
    unsigned char* tb = (unsigned char*)alloc((size_t)n * 64);     // fp8 u = t*dis
    float*    out = (float*)d_out;

    int initN = NGRAPH * 64;  // 8192 > NBF
    init_k<<<(initN + 255) / 256, 256, 0, stream>>>(cursorF, pooled, NBF);
    binA_k<<<GA, 1024, 0, stream>>>(src, dst, cursorF, binned, E, NBF);
    reorder_k<<<NBF, 256, 0, stream>>>(binned, cursorF, nodebeg, nodeend, dis, x, xs, n);

    mm12_k<<<(n + MMN - 1) / MMN, 256, 0, stream>>>(xs, nodebeg, nodeend,
            (const int*)binned, dis, W1, b1, W2, tb, n);
    gather2_k<<<(n * 32 + 255) / 256, 256, 0, stream>>>(tb, b2, nodebeg, nodeend,
            (const int*)binned, dis, batch, pooled, n);

    head_k<<<NGRAPH, 64, 0, stream>>>(pooled, batch, Wl, bl, out, n);
}

// Round 19
// 218.708 us; speedup vs baseline: 1.0518x; 1.0247x over previous
//
#include <hip/hip_runtime.h>
#include <math.h>

#define NGRAPH 128
#define NPB 128          // nodes per fine bucket
#define CAPB 6144        // fine bucket capacity (mean 4096, +32 sigma)
#define MMN 16           // nodes per mm12 block
#define TILEA 16384      // edges per binA workgroup (measured optimum; 8192 = +11 µs)
#define EPTA 16          // TILEA / 1024 threads

// ---------------- fp8 e4m3fn helpers (payload-only; accumulation stays f32) ----

__device__ inline unsigned char f2fp8(float f) {
    float a = fabsf(f);
    unsigned s = (__float_as_uint(f) >> 31) << 7;
    if (!(a > 0.f)) return (unsigned char)s;
    if (a >= 448.f) return (unsigned char)(s | 0x7e);
    int e = (int)(__float_as_uint(a) >> 23) - 127;
    if (e < -6) e = -6;
    // 2^(3-e) built from exponent bits (e in [-6,8] -> biased 122..136): exact, no exp2f
    float sc = __uint_as_float((unsigned)(130 - e) << 23);
    int q = (int)rintf(a * sc);   // RNE
    if (q >= 16) { e += 1; q = 8; }
    if (q <= 0) return (unsigned char)s;
    unsigned expb, man;
    if (q < 8) { expb = 0; man = (unsigned)q; }
    else { expb = (unsigned)(e + 7); man = (unsigned)(q - 8); }
    return (unsigned char)(s | (expb << 3) | man);
}

typedef float v2f __attribute__((ext_vector_type(2)));

// decode 4 fp8 (one u32) -> 4 f32, register-only (fallback path only)
__device__ inline void fp8x4_dec(unsigned u, float* o) {
#pragma unroll
    for (int k = 0; k < 4; ++k) {
        unsigned b = (u >> (8 * k)) & 0xffu;
        unsigned bits = ((b & 0x80u) << 24) | ((b & 0x7fu) << 20);
        o[k] = __uint_as_float(bits) * 0x1p+120f;
    }
}

// decode one fp8 row-quad (16 values) and accumulate with weight w in {0,1}.
__device__ inline void acc16(uint4 u, float w, v2f* a) {
#if __has_builtin(__builtin_amdgcn_cvt_pk_f32_fp8)
    v2f ws; ws.x = w; ws.y = w;
    a[0] += __builtin_amdgcn_cvt_pk_f32_fp8(u.x, false) * ws;
    a[1] += __builtin_amdgcn_cvt_pk_f32_fp8(u.x, true)  * ws;
    a[2] += __builtin_amdgcn_cvt_pk_f32_fp8(u.y, false) * ws;
    a[3] += __builtin_amdgcn_cvt_pk_f32_fp8(u.y, true)  * ws;
    a[4] += __builtin_amdgcn_cvt_pk_f32_fp8(u.z, false) * ws;
    a[5] += __builtin_amdgcn_cvt_pk_f32_fp8(u.z, true)  * ws;
    a[6] += __builtin_amdgcn_cvt_pk_f32_fp8(u.w, false) * ws;
    a[7] += __builtin_amdgcn_cvt_pk_f32_fp8(u.w, true)  * ws;
#else
    float* af = (float*)a;
    unsigned uu[4] = {u.x, u.y, u.z, u.w};
#pragma unroll
    for (int q = 0; q < 4; ++q) {
        float d[4]; fp8x4_dec(uu[q], d);
#pragma unroll
        for (int k = 0; k < 4; ++k) af[q * 4 + k] += d[k] * w;
    }
#endif
}

// ---------------- init: cursors + pooled zero ----------------

__global__ void init_k(int* __restrict__ cursorF, float* __restrict__ pooled, int NBF) {
    int i = blockIdx.x * blockDim.x + threadIdx.x;
    if (i < NBF) cursorF[i] = i * CAPB;
    if (i < NGRAPH * 64) pooled[i] = 0.0f;
}

// ---------------- single-pass fine binning, LDS-staged sorted output ----------
// r11 (verified): counting-sort the 16K-edge tile in LDS, copy out one WAVE
// per bucket-run as contiguous bursts (kills the 5-7x write amplification of
// scattered 4B stores, r9/r10). TILEA=16384 is the measured optimum (r17:
// 8192 cost +11 µs).
// Record: src (bits 0-16) | node-within-bucket (bits 17-23).

__global__ __launch_bounds__(1024) void binA_k(const int* __restrict__ src,
        const int* __restrict__ dst, int* cursorF, unsigned* __restrict__ binned,
        int E, int NBF) {
    __shared__ int lh[1024];          // histogram -> running local cursor
    __shared__ int startv[1024];      // local prefix (NBF+1 used)
    __shared__ int gdelta[1024];      // gbase - localstart per bucket
    __shared__ unsigned lout[TILEA];  // 64 KB staged sorted tile
    int tid = threadIdx.x;
    lh[tid] = 0;
    __syncthreads();
    int base = blockIdx.x * TILEA;
    int d[EPTA];
    int s[EPTA];
#pragma unroll
    for (int u = 0; u < EPTA; ++u) {
        int e = base + tid + u * 1024;
        d[u] = (e < E) ? dst[e] : -1;
        s[u] = (e < E) ? src[e] : 0;
    }
#pragma unroll
    for (int u = 0; u < EPTA; ++u)
        if (d[u] >= 0) atomicAdd(&lh[d[u] >> 7], 1);
    __syncthreads();
    // inclusive scan over NBF counts -> startv[0..NBF]
    if (tid <= NBF) startv[tid] = (tid == 0) ? 0 : lh[tid - 1];
    __syncthreads();
    for (int off = 1; off <= NBF; off <<= 1) {
        int v = 0;
        if (tid <= NBF && tid >= off) v = startv[tid - off];
        __syncthreads();
        if (tid <= NBF && tid >= off) startv[tid] += v;
        __syncthreads();
    }
    // claim global ranges; set local running cursors
    if (tid < NBF) {
        int cnt = lh[tid];
        int g = cnt ? atomicAdd(&cursorF[tid], cnt) : 0;
        gdelta[tid] = g - startv[tid];
        lh[tid] = startv[tid];
    }
    __syncthreads();
    // counting-sort scatter into LDS
#pragma unroll
    for (int u = 0; u < EPTA; ++u) {
        if (d[u] >= 0) {
            int p = atomicAdd(&lh[d[u] >> 7], 1);
            lout[p] = (unsigned)s[u] | ((unsigned)(d[u] & (NPB - 1)) << 17);
        }
    }
    __syncthreads();
    // copy out: one wave per bucket-run, lanes burst-write the run
    int wv = tid >> 6, ln = tid & 63;
    for (int bkt = wv; bkt < NBF; bkt += 16) {
        int ls = startv[bkt], le = lh[bkt];
        int gd = gdelta[bkt];
        for (int i = ls + ln; i < le; i += 64)
            binned[gd + i] = lout[i];
    }
}

// ---------------- per-fine-bucket counting sort (in-place) + xs = x*dis --------
// Single-LDS-buffer form (r16's lin-staging REVERTED: +48 KB LDS cut reorder
// occupancy 3->2 blocks/CU, +5 µs measured r18 vs r15 with clean controls;
// the avoided 12.8 MB re-read was L2-hot from binA anyway).

__global__ __launch_bounds__(256) void reorder_k(unsigned* __restrict__ binned,
        const int* __restrict__ cursorF, int* __restrict__ nodebeg,
        int* __restrict__ nodeend, float* __restrict__ dis,
        const float* __restrict__ x, float* __restrict__ xs, int n) {
    __shared__ int hist[NPB + 1];
    __shared__ int startv[NPB + 1];
    __shared__ unsigned lout[CAPB];
    int tid = threadIdx.x;
    int b = blockIdx.x;
    int beg = b * CAPB, end = cursorF[b];
    int total = end - beg;
    if (tid <= NPB) hist[tid] = 0;
    __syncthreads();
    for (int i = beg + tid; i < end; i += 256)
        atomicAdd(&hist[binned[i] >> 17], 1);
    __syncthreads();
    if (tid < NPB) startv[tid + 1] = hist[tid];
    if (tid == 0) startv[0] = 0;
    __syncthreads();
    for (int off = 1; off <= NPB; off <<= 1) {
        int v = 0;
        if (tid <= NPB && tid >= off) v = startv[tid - off];
        __syncthreads();
        if (tid <= NPB && tid >= off) startv[tid] += v;
        __syncthreads();
    }
    if (tid < NPB) hist[tid] = startv[tid];
    __syncthreads();
    for (int i = beg + tid; i < end; i += 256) {
        unsigned r = binned[i];
        int p = atomicAdd(&hist[r >> 17], 1);
        lout[p] = r & 0x1FFFFu;
    }
    __syncthreads();
    for (int jj = tid; jj < total; jj += 256)
        binned[beg + jj] = lout[jj];
    int node0 = b * NPB;
    if (tid < NPB) {
        int node = node0 + tid;
        if (node < n) {
            nodebeg[node] = beg + startv[tid];
            nodeend[node] = beg + startv[tid + 1];
            int deg = startv[tid + 1] - startv[tid];
            float d = rsqrtf((float)deg + 1.0f);
            dis[node] = d;
            xs[node * 3]     = x[node * 3] * d;
            xs[node * 3 + 1] = x[node * 3 + 1] * d;
            xs[node * 3 + 2] = x[node * 3 + 2] * d;
        }
    }
}

// ---------------- fused layer-1: gather(xs) + tb = fp8(dis * relu(y@W1+b1)@W2) ----
// r11 phase-2 (register W2 column; r12's packed variant regressed 44.5->66.8)
// + r15 4-deep phase-1 batch. Single tb (r16's channel split REVERTED: doubled
// csr stream defeated the L2-residency gain, +7.5 µs).

__global__ __launch_bounds__(256) void mm12_k(const float* __restrict__ xs,
        const int* __restrict__ nodebeg, const int* __restrict__ nodeend,
        const int* __restrict__ csr, const float* __restrict__ dis,
        const float* __restrict__ W1, const float* __restrict__ b1,
        const float* __restrict__ W2, unsigned char* __restrict__ tb, int n) {
    __shared__ __attribute__((aligned(16))) float hrow[4][64];
    __shared__ float4 ytile[MMN];
    int tid = threadIdx.x;
    int j = tid & 63;

    // register column of the weights (issued first; latency hides under phase 1)
    float w1r0 = W1[j], w1r1 = W1[64 + j], w1r2 = W1[128 + j], bbr = b1[j];
    float wreg[64];
#pragma unroll
    for (int k = 0; k < 64; ++k) wreg[k] = W2[k * 64 + j];

    // ---- phase 1: gather y for this block's 16 nodes (4-deep batch) ----
    int ns = tid >> 4;          // node slot 0..15
    int el = tid & 15;          // edge lane 0..15
    int gnode = blockIdx.x * MMN + ns;
    float a0 = 0.f, a1 = 0.f, a2 = 0.f;
    float dn = 0.f;
    int b = 0, e = 0;
    if (gnode < n) {
        dn = dis[gnode];
        b = nodebeg[gnode];
        e = nodeend[gnode];
    }
    for (int i = b + el; i < e; i += 64) {
        int i1 = i + 16, i2 = i + 32, i3 = i + 48;
        int s0 = csr[i];
        int s1 = (i1 < e) ? csr[i1] : s0;
        int s2 = (i2 < e) ? csr[i2] : s0;
        int s3 = (i3 < e) ? csr[i3] : s0;
        float m1 = (i1 < e) ? 1.f : 0.f;
        float m2 = (i2 < e) ? 1.f : 0.f;
        float m3 = (i3 < e) ? 1.f : 0.f;
        float p0 = xs[s0 * 3], p1 = xs[s0 * 3 + 1], p2 = xs[s0 * 3 + 2];
        float q0 = xs[s1 * 3], q1 = xs[s1 * 3 + 1], q2 = xs[s1 * 3 + 2];
        float r0 = xs[s2 * 3], r1 = xs[s2 * 3 + 1], r2 = xs[s2 * 3 + 2];
        float t0 = xs[s3 * 3], t1 = xs[s3 * 3 + 1], t2 = xs[s3 * 3 + 2];
        a0 += p0 + q0 * m1 + r0 * m2 + t0 * m3;
        a1 += p1 + q1 * m1 + r1 * m2 + t1 * m3;
        a2 += p2 + q2 * m1 + r2 * m2 + t2 * m3;
    }
    // reduce over the 16 edge lanes (lane-group-local xor shuffles)
#pragma unroll
    for (int off = 1; off <= 8; off <<= 1) {
        a0 += __shfl_xor(a0, off);
        a1 += __shfl_xor(a1, off);
        a2 += __shfl_xor(a2, off);
    }
    if (el == 0 && gnode < n) {
        // self term: dn*x[node] == xs[node]; y = dn*(sum + xs[node])
        ytile[ns] = make_float4(dn * (a0 + xs[gnode * 3]),
                                dn * (a1 + xs[gnode * 3 + 1]),
                                dn * (a2 + xs[gnode * 3 + 2]), dn);
    }
    __syncthreads();   // the ONLY block barrier: ytile ready

    // ---- phase 2: MLP (hrow is wave-private; w2 column in registers) ----
    int nl = tid >> 6;
    for (int it = 0; it < MMN / 4; ++it) {
        int slot = it * 4 + nl;
        int node = blockIdx.x * MMN + slot;
        float4 yv = ytile[slot];
        float h = fmaxf(yv.x * w1r0 + yv.y * w1r1 + yv.z * w1r2 + bbr, 0.0f);
        hrow[nl][j] = h;
        __builtin_amdgcn_wave_barrier();   // compiler fence only (no HW cost)
        float acc = 0.0f;
#pragma unroll
        for (int k = 0; k < 64; k += 4) {
            float4 h4 = *(const float4*)&hrow[nl][k];
            acc += h4.x * wreg[k + 0];
            acc += h4.y * wreg[k + 1];
            acc += h4.z * wreg[k + 2];
            acc += h4.w * wreg[k + 3];
        }
        if (node < n) tb[node * 64 + j] = f2fp8(acc * yv.w);  // store u = t*dis(node)
        __builtin_amdgcn_wave_barrier();   // keep next-iter hrow write below these reads
    }
}

// ---------------- layer 2 aggregate + fused relu-pool (r15 form, verified) ----
// 2 nodes/wave; esub in [0,8) x c4 in [0,4); 8-deep staging (64 slots = one
// latency exposure); 3-stage reduce-scatter (xor 4/8/16); relu + LDS graph-bin
// pooling, one flush of <=256 global atomics per block (NOT r4's per-lane
// atomic storm). tb holds u = t*dis so edge weight is 1 (r9 pre-scaling).

__global__ __launch_bounds__(256) void gather2_k(const unsigned char* __restrict__ tb,
        const float* __restrict__ b2, const int* __restrict__ nodebeg,
        const int* __restrict__ nodeend, const int* __restrict__ csr,
        const float* __restrict__ dis, const int* __restrict__ batch,
        float* __restrict__ pooled, int n) {
    __shared__ float pacc[4][64];
    __shared__ int gbase;
    int tid = threadIdx.x;
    ((float*)pacc)[tid] = 0.f;
    int node0 = blockIdx.x * 8;              // 8 nodes per 256-thread block
    if (tid == 0) gbase = batch[node0 < n ? node0 : (n - 1)];
    __syncthreads();

    int g = blockIdx.x * blockDim.x + tid;
    int node = g >> 5;                       // 32 lanes per node
    int l32 = tid & 31;
    int c4 = l32 & 3, esub = l32 >> 2;       // esub in [0,8)
    if (node < n) {
        const uint4* t16 = (const uint4*)tb; // row = 4 uint4 (64 fp8)
        float dn = dis[node];
        int b = nodebeg[node], e = nodeend[node];
        v2f av[8];
#pragma unroll
        for (int k = 0; k < 8; ++k) { av[k].x = 0.f; av[k].y = 0.f; }
        // slots i+esub+8d, d=0..7 cover i..i+63 exactly once; slot idx==e carries
        // the self-loop (s=node, weight 1); slots > e weight 0.
        for (int i = b; i < e + 1; i += 64) {
            int i0 = i + esub;
            int s0 = (i0      < e) ? csr[i0]      : node;
            int s1 = (i0 + 8  < e) ? csr[i0 + 8]  : node;
            int s2 = (i0 + 16 < e) ? csr[i0 + 16] : node;
            int s3 = (i0 + 24 < e) ? csr[i0 + 24] : node;
            int s4 = (i0 + 32 < e) ? csr[i0 + 32] : node;
            int s5 = (i0 + 40 < e) ? csr[i0 + 40] : node;
            int s6 = (i0 + 48 < e) ? csr[i0 + 48] : node;
            int s7 = (i0 + 56 < e) ? csr[i0 + 56] : node;
            uint4 u0 = t16[s0 * 4 + c4];
            uint4 u1 = t16[s1 * 4 + c4];
            uint4 u2 = t16[s2 * 4 + c4];
            uint4 u3 = t16[s3 * 4 + c4];
            uint4 u4 = t16[s4 * 4 + c4];
            uint4 u5 = t16[s5 * 4 + c4];
            uint4 u6 = t16[s6 * 4 + c4];
            uint4 u7 = t16[s7 * 4 + c4];
            acc16(u0, (i0      <= e) ? 1.f : 0.f, av);
            acc16(u1, (i0 + 8  <= e) ? 1.f : 0.f, av);
            acc16(u2, (i0 + 16 <= e) ? 1.f : 0.f, av);
            acc16(u3, (i0 + 24 <= e) ? 1.f : 0.f, av);
            acc16(u4, (i0 + 32 <= e) ? 1.f : 0.f, av);
            acc16(u5, (i0 + 40 <= e) ? 1.f : 0.f, av);
            acc16(u6, (i0 + 48 <= e) ? 1.f : 0.f, av);
            acc16(u7, (i0 + 56 <= e) ? 1.f : 0.f, av);
        }
        float* a = (float*)av;               // a[k] = channel c4*16 + k
        // reduce-scatter over the 8 esub lanes (intra-half xor shuffles).
        {
            bool hi = (esub & 1) != 0;       // stage off=4 (esub bit0)
#pragma unroll
            for (int t = 0; t < 8; ++t) {
                float send = hi ? a[t] : a[8 + t];
                float r = __shfl_xor(send, 4);
                a[t] = (hi ? a[8 + t] : a[t]) + r;
            }
        }
        {
            bool hi = (esub & 2) != 0;       // stage off=8 (esub bit1)
#pragma unroll
            for (int t = 0; t < 4; ++t) {
                float send = hi ? a[t] : a[4 + t];
                float r = __shfl_xor(send, 8);
                a[t] = (hi ? a[4 + t] : a[t]) + r;
            }
        }
        {
            bool hi = (esub & 4) != 0;       // stage off=16 (esub bit2)
#pragma unroll
            for (int t = 0; t < 2; ++t) {
                float send = hi ? a[t] : a[2 + t];
                float r = __shfl_xor(send, 16);
                a[t] = (hi ? a[2 + t] : a[t]) + r;
            }
        }
        // lane holds channels cb, cb+1: cb = bit0*8 + bit1*4 + bit2*2 (even 0..14)
        int cb = ((esub & 1) << 3) | ((esub & 2) << 1) | ((esub & 4) >> 1);
        int ch = c4 * 16 + cb;
        v2f bv = *(const v2f*)&b2[ch];
        float v0 = fmaxf(dn * a[0] + bv.x, 0.f);
        float v1 = fmaxf(dn * a[1] + bv.y, 0.f);
        int gid = batch[node];
        int bin = gid - gbase;
        if (bin < 4) {
            atomicAdd(&pacc[bin][ch], v0);
            atomicAdd(&pacc[bin][ch + 1], v1);
        } else {   // pathological tiny-graph fallback (practically never)
            atomicAdd(&pooled[gid * 64 + ch], v0);
            atomicAdd(&pooled[gid * 64 + ch + 1], v1);
        }
    }
    __syncthreads();
    // flush: 256 threads cover 4 bins x 64 channels; skip empty (relu >= 0)
    int fbin = tid >> 6, fch = tid & 63;
    float fv = pacc[fbin][fch];
    if (fv != 0.f) atomicAdd(&pooled[(gbase + fbin) * 64 + fch], fv);
}

// ---------------- head ----------------

__device__ inline int lower_bound_i(const int* a, int n, int key) {
    int lo = 0, hi = n;
    while (lo < hi) {
        int mid = (lo + hi) >> 1;
        if (a[mid] < key) lo = mid + 1; else hi = mid;
    }
    return lo;
}

__global__ void head_k(const float* __restrict__ pooled, const int* __restrict__ batch,
                       const float* __restrict__ Wl, const float* __restrict__ bl,
                       float* __restrict__ out, int n) {
    int g = blockIdx.x, t = threadIdx.x;
    __shared__ float p[64];
    __shared__ float logit[8];
    int start = lower_bound_i(batch, n, g);
    int end   = lower_bound_i(batch, n, g + 1);
    float cnt = fmaxf((float)(end - start), 1.0f);
    p[t] = pooled[g * 64 + t] / cnt;
    __syncthreads();
    if (t < 6) {
        float a = bl[t];
        for (int k = 0; k < 64; ++k) a += p[k] * Wl[k * 6 + t];
        logit[t] = a;
    }
    __syncthreads();
    if (t == 0) {
        float m = logit[0];
        for (int j = 1; j < 6; ++j) m = fmaxf(m, logit[j]);
        float s = 0.0f;
        for (int j = 0; j < 6; ++j) s += expf(logit[j] - m);
        float lse = m + logf(s);
        for (int j = 0; j < 6; ++j) out[g * 6 + j] = logit[j] - lse;
    }
}

// ---------------- launch ----------------

extern "C" void kernel_launch(void* const* d_in, const int* in_sizes, int n_in,
                              void* d_out, int out_size, void* d_ws, size_t ws_size,
                              hipStream_t stream) {
    const float* x     = (const float*)d_in[0];
    const int*   ei    = (const int*)d_in[1];
    const int*   batch = (const int*)d_in[2];
    const float* W1    = (const float*)d_in[3];
    const float* b1    = (const float*)d_in[4];
    const float* W2    = (const float*)d_in[5];
    const float* b2    = (const float*)d_in[6];
    const float* Wl    = (const float*)d_in[7];
    const float* bl    = (const float*)d_in[8];

    int n = in_sizes[0] / 3;
    int E = in_sizes[1] / 2;
    const int* src = ei;
    const int* dst = ei + E;

    int NBF = (n + NPB - 1) / NPB;          // fine buckets (782)
    int GA = (E + TILEA - 1) / TILEA;       // binA blocks (196)

    char* ws = (char*)d_ws;
    size_t o = 0;
    auto alloc = [&](size_t bytes) -> void* {
        void* p = ws + o;
        o += (bytes + 255) & ~(size_t)255;
        return p;
    };
    int*      cursorF = (int*)alloc((size_t)NBF * 4);
    float*    dis     = (float*)alloc((size_t)n * 4);
    int*      nodebeg = (int*)alloc((size_t)n * 4);
    int*      nodeend = (int*)alloc((size_t)n * 4);
    float*    xs      = (float*)alloc((size_t)n * 3 * 4);
    float*    pooled  = (float*)alloc((size_t)NGRAPH * 64 * 4);
    unsigned* binned  = (unsigned*)alloc((size_t)NBF * CAPB * 4);  // becomes csr in-place
    unsigned char* tb = (unsigned char*)alloc((size_t)n * 64);     // fp8 u = t*dis
    float*    out = (float*)d_out;

    int initN = NGRAPH * 64;  // 8192 > NBF
    init_k<<<(initN + 255) / 256, 256, 0, stream>>>(cursorF, pooled, NBF);
    binA_k<<<GA, 1024, 0, stream>>>(src, dst, cursorF, binned, E, NBF);
    reorder_k<<<NBF, 256, 0, stream>>>(binned, cursorF, nodebeg, nodeend, dis, x, xs, n);

    mm12_k<<<(n + MMN - 1) / MMN, 256, 0, stream>>>(xs, nodebeg, nodeend,
            (const int*)binned, dis, W1, b1, W2, tb, n);
    gather2_k<<<(n * 32 + 255) / 256, 256, 0, stream>>>(tb, b2, nodebeg, nodeend,
            (const int*)binned, dis, batch, pooled, n);

    head_k<<<NGRAPH, 64, 0, stream>>>(pooled, batch, Wl, bl, out, n);
}